// Round 4
// baseline (13927.022 us; speedup 1.0000x reference)
//
#include <hip/hip_runtime.h>
#include <hip/hip_cooperative_groups.h>
#include <hip/hip_bf16.h>
#include <math.h>

namespace cg = cooperative_groups;

// Sinkhorn distance, B=4, P1=P2=2048, D=64, EPS=0.1, 100 iterations.
// d_out layout: cost[4] | pi[4*2048*2048] | C[4*2048*2048]
//
// v3b: single cooperative kernel holds C (x KS) in REGISTERS for all 100
// iterations. 512 blocks x 256 threads (2 blocks/CU co-resident): block owns
// 16 rows, thread t owns cols [8t,8t+8) -> cK[16][8] = 128 VGPR.
// Per iteration:
//   phase A: block-local exact row-LSE -> u*KS in regs (u never hits memory).
//   phase B: thread-local col-LSE partials over its 16 rows -> part (8MB).
//   grid.sync; 16-threads/col merge of 128 partials -> v; grid.sync.
// Fused epilogue: pi = exp2(urK + vK - cK), cost = sum(pi*C).
// Fallback: if cooperative launch is rejected, run the proven v2 path
// (per-iter sweep + reduce kernels + final_pi) — same work, deterministic.

#define P 2048
#define D 64
#define B 4
#define NB 512       // blocks: 128 per batch
#define ITERS 100
#define EPS 0.1f
// (1/eps) * log2(e)
#define KS 14.426950408889634f
// eps * ln(2) == 1/KS
#define EL2 0.06931471805599453f

#define EX2 __builtin_amdgcn_exp2f   // v_exp_f32 (2^x)
#define LG2 __builtin_amdgcn_logf    // v_log_f32 (log2 x)

// ---------------------------------------------------------------- cost matrix
// grid (32, 32, 4), block 256. 64x64 tile, 4x4 per thread.
__global__ __launch_bounds__(256) void cost_kernel(
    const float* __restrict__ X, const float* __restrict__ Y,
    float* __restrict__ C) {
  __shared__ float xs[64][65];
  __shared__ float ys[64][65];
  const int b = blockIdx.z;
  const int i0 = blockIdx.y * 64;
  const int j0 = blockIdx.x * 64;
  const float* Xb = X + ((size_t)b * P + i0) * D;
  const float* Yb = Y + ((size_t)b * P + j0) * D;
  const int t = threadIdx.x;
#pragma unroll
  for (int n = 0; n < 4; n++) {
    int e4 = t + n * 256;
    float4 xv = ((const float4*)Xb)[e4];
    float4 yv = ((const float4*)Yb)[e4];
    int r = e4 >> 4;
    int k = (e4 & 15) * 4;
    xs[r][k] = xv.x; xs[r][k + 1] = xv.y; xs[r][k + 2] = xv.z; xs[r][k + 3] = xv.w;
    ys[r][k] = yv.x; ys[r][k + 1] = yv.y; ys[r][k + 2] = yv.z; ys[r][k + 3] = yv.w;
  }
  __syncthreads();
  const int tx = t & 15;
  const int ty = t >> 4;
  float acc[4][4] = {};
#pragma unroll
  for (int k = 0; k < D; k++) {
    float a[4], bb[4];
#pragma unroll
    for (int r = 0; r < 4; r++) a[r] = xs[ty * 4 + r][k];
#pragma unroll
    for (int c = 0; c < 4; c++) bb[c] = ys[tx * 4 + c][k];
#pragma unroll
    for (int r = 0; r < 4; r++)
#pragma unroll
      for (int c = 0; c < 4; c++) {
        float d = a[r] - bb[c];
        acc[r][c] = fmaf(d, d, acc[r][c]);
      }
  }
#pragma unroll
  for (int r = 0; r < 4; r++) {
    float4 o = make_float4(acc[r][0], acc[r][1], acc[r][2], acc[r][3]);
    *(float4*)&C[((size_t)b * P + i0 + ty * 4 + r) * P + j0 + tx * 4] = o;
  }
}

// ------------------------------------------------------- fused Sinkhorn loop
__global__ __launch_bounds__(256, 2) void sinkhorn_fused(
    const float* __restrict__ C, float* __restrict__ v,
    float2* __restrict__ part, float* __restrict__ pi,
    float* __restrict__ cost, float elog) {
  cg::grid_group grid = cg::this_grid();
  const int bid = blockIdx.x;
  const int rows0 = bid * 16;          // global row base (b*2048 + row)
  const int b = rows0 >> 11;           // batch
  const int kb = bid & 127;            // block index within batch
  const int t = threadIdx.x;
  const int lane = t & 63;
  const int w = t >> 6;

  __shared__ __align__(16) float redm[4][16];
  __shared__ __align__(16) float reds[4][16];
  __shared__ float sa[4];

  // ---- load C rows once, pre-scaled by KS: cK[r][j] = C[rows0+r][8t+j]*KS
  float cK[16][8];
  {
    const float* Cb = C + (size_t)rows0 * P + t * 8;
#pragma unroll
    for (int r = 0; r < 16; r++) {
      float4 a = *(const float4*)(Cb + (size_t)r * P);
      float4 q = *(const float4*)(Cb + (size_t)r * P + 4);
      cK[r][0] = a.x * KS; cK[r][1] = a.y * KS; cK[r][2] = a.z * KS; cK[r][3] = a.w * KS;
      cK[r][4] = q.x * KS; cK[r][5] = q.y * KS; cK[r][6] = q.z * KS; cK[r][7] = q.w * KS;
    }
  }

  const float* vbase = v + ((size_t)b << 11) + t * 8;
  float2* partw = part + (size_t)kb * (B * P) + ((size_t)b << 11) + t * 8;
  float urK[16];

#pragma unroll 1
  for (int it = 0; it < ITERS; it++) {
    // ---- v for my 8 cols, pre-scaled (v=0 at it=0 via memset)
    float vvK[8];
    {
      float4 a = *(const float4*)(vbase);
      float4 q = *(const float4*)(vbase + 4);
      vvK[0] = a.x * KS; vvK[1] = a.y * KS; vvK[2] = a.z * KS; vvK[3] = a.w * KS;
      vvK[4] = q.x * KS; vvK[5] = q.y * KS; vvK[6] = q.z * KS; vvK[7] = q.w * KS;
    }

    // ---- phase A: row LSE of z = vvK - cK (log2 domain), exact max
    float bm[16];
#pragma unroll
    for (int r = 0; r < 16; r++) {
      float m = vvK[0] - cK[r][0];
#pragma unroll
      for (int j = 1; j < 8; j++) m = fmaxf(m, vvK[j] - cK[r][j]);
#pragma unroll
      for (int off = 32; off; off >>= 1) m = fmaxf(m, __shfl_xor(m, off));
      bm[r] = m;
    }
    if (lane == 0) {
#pragma unroll
      for (int r = 0; r < 16; r++) redm[w][r] = bm[r];
    }
    __syncthreads();
#pragma unroll
    for (int r4 = 0; r4 < 4; r4++) {
      float4 m0 = *(const float4*)&redm[0][r4 * 4];
      float4 m1 = *(const float4*)&redm[1][r4 * 4];
      float4 m2 = *(const float4*)&redm[2][r4 * 4];
      float4 m3 = *(const float4*)&redm[3][r4 * 4];
      bm[r4 * 4 + 0] = fmaxf(fmaxf(m0.x, m1.x), fmaxf(m2.x, m3.x));
      bm[r4 * 4 + 1] = fmaxf(fmaxf(m0.y, m1.y), fmaxf(m2.y, m3.y));
      bm[r4 * 4 + 2] = fmaxf(fmaxf(m0.z, m1.z), fmaxf(m2.z, m3.z));
      bm[r4 * 4 + 3] = fmaxf(fmaxf(m0.w, m1.w), fmaxf(m2.w, m3.w));
    }
    float ls[16];
#pragma unroll
    for (int r = 0; r < 16; r++) {
      float s = 0.f;
#pragma unroll
      for (int j = 0; j < 8; j++) s += EX2(vvK[j] - cK[r][j] - bm[r]);
#pragma unroll
      for (int off = 32; off; off >>= 1) s += __shfl_xor(s, off);
      ls[r] = s;
    }
    if (lane == 0) {
#pragma unroll
      for (int r = 0; r < 16; r++) reds[w][r] = ls[r];
    }
    __syncthreads();
#pragma unroll
    for (int r4 = 0; r4 < 4; r4++) {
      float4 s0 = *(const float4*)&reds[0][r4 * 4];
      float4 s1 = *(const float4*)&reds[1][r4 * 4];
      float4 s2 = *(const float4*)&reds[2][r4 * 4];
      float4 s3 = *(const float4*)&reds[3][r4 * 4];
      urK[r4 * 4 + 0] = (elog - EL2 * (bm[r4 * 4 + 0] + LG2((s0.x + s1.x) + (s2.x + s3.x)))) * KS;
      urK[r4 * 4 + 1] = (elog - EL2 * (bm[r4 * 4 + 1] + LG2((s0.y + s1.y) + (s2.y + s3.y)))) * KS;
      urK[r4 * 4 + 2] = (elog - EL2 * (bm[r4 * 4 + 2] + LG2((s0.z + s1.z) + (s2.z + s3.z)))) * KS;
      urK[r4 * 4 + 3] = (elog - EL2 * (bm[r4 * 4 + 3] + LG2((s0.w + s1.w) + (s2.w + s3.w)))) * KS;
    }

    // ---- phase B: thread-local column-LSE partial over my 16 rows
    float2 pw[8];
#pragma unroll
    for (int cc = 0; cc < 8; cc++) {
      float z[16];
#pragma unroll
      for (int r = 0; r < 16; r++) z[r] = urK[r] - cK[r][cc];
      float tm = z[0];
#pragma unroll
      for (int r = 1; r < 16; r++) tm = fmaxf(tm, z[r]);
      float s = 0.f;
#pragma unroll
      for (int r = 0; r < 16; r++) s += EX2(z[r] - tm);
      pw[cc] = make_float2(tm, s);
    }
    {
      float4* p4 = (float4*)partw;
#pragma unroll
      for (int i = 0; i < 4; i++)
        p4[i] = make_float4(pw[2 * i].x, pw[2 * i].y, pw[2 * i + 1].x, pw[2 * i + 1].y);
    }

    grid.sync();

    // ---- merge 128 partials per column -> v. 16 threads/col, all blocks.
    {
      const int gt = bid * 256 + t;     // 0..131071
      const int col = gt >> 4;          // global col 0..8191
      const int seg = gt & 15;
      const float2* pk = part + (size_t)(seg * 8) * (B * P) + col;
      float m = -__builtin_inff();
      float s = 0.f;
#pragma unroll
      for (int k = 0; k < 8; k++) {
        float2 p2 = pk[(size_t)k * (B * P)];
        float M = fmaxf(m, p2.x);
        s = s * EX2(m - M) + p2.y * EX2(p2.x - M);
        m = M;
      }
#pragma unroll
      for (int off = 1; off <= 8; off <<= 1) {
        float om = __shfl_xor(m, off);
        float os = __shfl_xor(s, off);
        float M = fmaxf(m, om);
        s = s * EX2(m - M) + os * EX2(om - M);
        m = M;
      }
      if (seg == 0) v[col] = elog - EL2 * (m + LG2(s));
    }

    grid.sync();
  }

  // ---- fused epilogue: pi = exp2(urK + vK - cK); cost = sum(pi * C)
  {
    float vvK[8];
    float4 a = *(const float4*)(vbase);
    float4 q = *(const float4*)(vbase + 4);
    vvK[0] = a.x * KS; vvK[1] = a.y * KS; vvK[2] = a.z * KS; vvK[3] = a.w * KS;
    vvK[4] = q.x * KS; vvK[5] = q.y * KS; vvK[6] = q.z * KS; vvK[7] = q.w * KS;

    float acc = 0.f;
    float* pib = pi + (size_t)rows0 * P + t * 8;
#pragma unroll
    for (int r = 0; r < 16; r++) {
      float p[8];
#pragma unroll
      for (int j = 0; j < 8; j++) {
        p[j] = EX2(urK[r] + vvK[j] - cK[r][j]);
        acc = fmaf(p[j], cK[r][j], acc);
      }
      *(float4*)(pib + (size_t)r * P) = make_float4(p[0], p[1], p[2], p[3]);
      *(float4*)(pib + (size_t)r * P + 4) = make_float4(p[4], p[5], p[6], p[7]);
    }
    acc *= EL2;  // un-scale: cK = C*KS, 1/KS == EL2
#pragma unroll
    for (int off = 32; off; off >>= 1) acc += __shfl_xor(acc, off);
    if (lane == 0) sa[w] = acc;
    __syncthreads();
    if (t == 0) atomicAdd(cost + b, (sa[0] + sa[1]) + (sa[2] + sa[3]));
  }
}

// ====================== v2 fallback path (proven @2750us) ===================
__global__ __launch_bounds__(256, 2) void sweep_kernel(
    const float* __restrict__ C, const float* __restrict__ v,
    float* __restrict__ u, float2* __restrict__ part, float elog) {
  const int bid = blockIdx.x;
  const int grow0 = bid * 16;
  const int b = grow0 >> 11;
  const int kb = bid & 127;
  const int t = threadIdx.x;
  const int lane = t & 63;
  const int w = t >> 6;

  float vvK[8];
  {
    const float4* vp = (const float4*)(v + ((size_t)b << 11) + t * 8);
    float4 a = vp[0], c4 = vp[1];
    vvK[0] = a.x * KS;  vvK[1] = a.y * KS;  vvK[2] = a.z * KS;  vvK[3] = a.w * KS;
    vvK[4] = c4.x * KS; vvK[5] = c4.y * KS; vvK[6] = c4.z * KS; vvK[7] = c4.w * KS;
  }

  float colm[8], cols[8];
#pragma unroll
  for (int j = 0; j < 8; j++) { colm[j] = -__builtin_inff(); cols[j] = 0.f; }

  __shared__ float redm[4][8];
  __shared__ float reds[4][8];

#pragma unroll
  for (int g = 0; g < 2; g++) {
    float cK[8][8];
    const float* Cb = C + ((size_t)(grow0 + g * 8)) * P + t * 8;
#pragma unroll
    for (int r = 0; r < 8; r++) {
      float4 a = *(const float4*)(Cb + (size_t)r * P);
      float4 q = *(const float4*)(Cb + (size_t)r * P + 4);
      cK[r][0] = a.x * KS; cK[r][1] = a.y * KS; cK[r][2] = a.z * KS; cK[r][3] = a.w * KS;
      cK[r][4] = q.x * KS; cK[r][5] = q.y * KS; cK[r][6] = q.z * KS; cK[r][7] = q.w * KS;
    }
    float lm[8];
#pragma unroll
    for (int r = 0; r < 8; r++) {
      float m = vvK[0] - cK[r][0];
#pragma unroll
      for (int j = 1; j < 8; j++) m = fmaxf(m, vvK[j] - cK[r][j]);
#pragma unroll
      for (int off = 32; off; off >>= 1) m = fmaxf(m, __shfl_xor(m, off));
      lm[r] = m;
    }
    if (lane == 0) {
#pragma unroll
      for (int r = 0; r < 8; r++) redm[w][r] = lm[r];
    }
    __syncthreads();
    float bm[8];
#pragma unroll
    for (int r = 0; r < 8; r++)
      bm[r] = fmaxf(fmaxf(redm[0][r], redm[1][r]),
                    fmaxf(redm[2][r], redm[3][r]));
    float ls[8];
#pragma unroll
    for (int r = 0; r < 8; r++) {
      float s = 0.f;
#pragma unroll
      for (int j = 0; j < 8; j++) s += EX2(vvK[j] - cK[r][j] - bm[r]);
#pragma unroll
      for (int off = 32; off; off >>= 1) s += __shfl_xor(s, off);
      ls[r] = s;
    }
    if (lane == 0) {
#pragma unroll
      for (int r = 0; r < 8; r++) reds[w][r] = ls[r];
    }
    __syncthreads();
    float urK[8];
    float urr[8];
#pragma unroll
    for (int r = 0; r < 8; r++) {
      float S = (reds[0][r] + reds[1][r]) + (reds[2][r] + reds[3][r]);
      urr[r] = elog - EL2 * (bm[r] + LG2(S));
      urK[r] = urr[r] * KS;
    }
    if (t == 0) {
#pragma unroll
      for (int r = 0; r < 8; r++) u[grow0 + g * 8 + r] = urr[r];
    }
#pragma unroll
    for (int cc = 0; cc < 8; cc++) {
      float z[8];
#pragma unroll
      for (int r = 0; r < 8; r++) z[r] = urK[r] - cK[r][cc];
      float tm = z[0];
#pragma unroll
      for (int r = 1; r < 8; r++) tm = fmaxf(tm, z[r]);
      float M = fmaxf(colm[cc], tm);
      float s = 0.f;
#pragma unroll
      for (int r = 0; r < 8; r++) s += EX2(z[r] - M);
      cols[cc] = cols[cc] * EX2(colm[cc] - M) + s;
      colm[cc] = M;
    }
    __syncthreads();
  }
#pragma unroll
  for (int cc = 0; cc < 8; cc++) {
    part[(size_t)kb * (B * P) + (size_t)b * P + t * 8 + cc] =
        make_float2(colm[cc], cols[cc]);
  }
}

__global__ __launch_bounds__(256) void reduce_v(
    const float2* __restrict__ part, float* __restrict__ v, float elog) {
  const int gtid = blockIdx.x * 256 + threadIdx.x;
  const int col = gtid >> 2;
  const int seg = gtid & 3;
  const int k0 = seg * 32;
  float m = -__builtin_inff();
  float s = 0.f;
#pragma unroll 8
  for (int k = 0; k < 32; k++) {
    float2 p = part[(size_t)(k0 + k) * (B * P) + col];
    float M = fmaxf(m, p.x);
    s = s * EX2(m - M) + p.y * EX2(p.x - M);
    m = M;
  }
#pragma unroll
  for (int off = 1; off <= 2; off <<= 1) {
    float om = __shfl_xor(m, off);
    float os = __shfl_xor(s, off);
    float M = fmaxf(m, om);
    s = s * EX2(m - M) + os * EX2(om - M);
    m = M;
  }
  if (seg == 0) v[col] = elog - EL2 * (m + LG2(s));
}

__global__ __launch_bounds__(256) void final_pi(
    const float* __restrict__ C, const float* __restrict__ u,
    const float* __restrict__ v, float* __restrict__ pi,
    float* __restrict__ cost) {
  const int row = blockIdx.x;
  const int b = row >> 11;
  const int t = threadIdx.x;
  const float4* cp = (const float4*)(C + (size_t)row * P);
  const float4* vp = (const float4*)(v + ((size_t)b << 11));
  float4* pp = (float4*)(pi + (size_t)row * P);
  const float ui = u[row];
  float acc = 0.f;
#pragma unroll
  for (int n = 0; n < 2; n++) {
    float4 c = cp[t + n * 256];
    float4 vv = vp[t + n * 256];
    float4 p;
    p.x = EX2((ui + vv.x - c.x) * KS);
    p.y = EX2((ui + vv.y - c.y) * KS);
    p.z = EX2((ui + vv.z - c.z) * KS);
    p.w = EX2((ui + vv.w - c.w) * KS);
    acc += p.x * c.x + p.y * c.y + p.z * c.z + p.w * c.w;
    pp[t + n * 256] = p;
  }
#pragma unroll
  for (int off = 32; off; off >>= 1) acc += __shfl_xor(acc, off);
  __shared__ float sa[4];
  if ((t & 63) == 0) sa[t >> 6] = acc;
  __syncthreads();
  if (t == 0) atomicAdd(cost + b, sa[0] + sa[1] + sa[2] + sa[3]);
}

// -------------------------------------------------------------------- launch
extern "C" void kernel_launch(void* const* d_in, const int* in_sizes, int n_in,
                              void* d_out, int out_size, void* d_ws,
                              size_t ws_size, hipStream_t stream) {
  const float* x = (const float*)d_in[0];
  const float* y = (const float*)d_in[1];
  float* out = (float*)d_out;
  float* cost = out;                          // [4]
  float* pi = out + 4;                        // [B*P*P], dead until epilogue
  float* Cmat = out + 4 + (size_t)B * P * P;  // [B*P*P]

  float2* part = (float2*)pi;                 // 128*8192 float2 = 8MB scratch
  float* v = (float*)d_ws;                    // [8192]
  float* u = v + B * P;                       // [8192] (fallback path only)

  hipMemsetAsync(v, 0, B * P * sizeof(float), stream);
  hipMemsetAsync(cost, 0, 4 * sizeof(float), stream);

  dim3 cgrid(P / 64, P / 64, B);
  cost_kernel<<<cgrid, 256, 0, stream>>>(x, y, Cmat);

  float elog = EPS * logf(1.0f / (float)P + 1e-8f);

  void* args[] = {(void*)&Cmat, (void*)&v, (void*)&part,
                  (void*)&pi, (void*)&cost, (void*)&elog};
  hipError_t err = hipLaunchCooperativeKernel((void*)sinkhorn_fused, dim3(NB),
                                              dim3(256), args, 0, stream);
  if (err != hipSuccess) {
    // Fallback: proven v2 multi-launch path (same math, same outputs).
    for (int it = 0; it < ITERS; it++) {
      sweep_kernel<<<B * P / 16, 256, 0, stream>>>(Cmat, v, u, part, elog);
      reduce_v<<<B * P * 4 / 256, 256, 0, stream>>>(part, v, elog);
    }
    final_pi<<<B * P, 256, 0, stream>>>(Cmat, u, v, pi, cost);
  }
}

// Round 5
// 4049.741 us; speedup vs baseline: 3.4390x; 3.4390x over previous
//
#include <hip/hip_runtime.h>
#include <hip/hip_bf16.h>
#include <math.h>

// Sinkhorn distance, B=4, P1=P2=2048, D=64, EPS=0.1, 100 iterations.
// d_out layout: cost[4] | pi[4*2048*2048] | C[4*2048*2048]
//
// v4: back to the proven multi-kernel v2 structure (v3 cooperative was 5x
// slower: grid.sync latency at 2 blocks/CU). Changes vs v2:
//  - sweep8: 8 rows/block -> 1024 blocks (4 blocks/CU, 16 waves/CU) for
//    better memory-latency hiding on the 67MB/iter C stream.
//  - reduce_v2: coalesced partial merge (wave = one 64-col seg), 128 blocks.
//  - final_pi2: 4 rows/block, v cached per thread, 1 atomic/block.
// Math identical to v2 (passed): log2-domain exact-max LSE, u/eps term
// cancels so u_new = elog - eps*LSE_j((v_j - C_ij)/eps); likewise v.

#define P 2048
#define D 64
#define B 4
#define ITERS 100
#define EPS 0.1f
// (1/eps) * log2(e)
#define KS 14.426950408889634f
// eps * ln(2) == 1/KS
#define EL2 0.06931471805599453f

#define EX2 __builtin_amdgcn_exp2f   // v_exp_f32 (2^x)
#define LG2 __builtin_amdgcn_logf    // v_log_f32 (log2 x)

// ---------------------------------------------------------------- cost matrix
// grid (32, 32, 4), block 256. 64x64 tile, 4x4 per thread.
__global__ __launch_bounds__(256) void cost_kernel(
    const float* __restrict__ X, const float* __restrict__ Y,
    float* __restrict__ C) {
  __shared__ float xs[64][65];
  __shared__ float ys[64][65];
  const int b = blockIdx.z;
  const int i0 = blockIdx.y * 64;
  const int j0 = blockIdx.x * 64;
  const float* Xb = X + ((size_t)b * P + i0) * D;
  const float* Yb = Y + ((size_t)b * P + j0) * D;
  const int t = threadIdx.x;
#pragma unroll
  for (int n = 0; n < 4; n++) {
    int e4 = t + n * 256;
    float4 xv = ((const float4*)Xb)[e4];
    float4 yv = ((const float4*)Yb)[e4];
    int r = e4 >> 4;
    int k = (e4 & 15) * 4;
    xs[r][k] = xv.x; xs[r][k + 1] = xv.y; xs[r][k + 2] = xv.z; xs[r][k + 3] = xv.w;
    ys[r][k] = yv.x; ys[r][k + 1] = yv.y; ys[r][k + 2] = yv.z; ys[r][k + 3] = yv.w;
  }
  __syncthreads();
  const int tx = t & 15;
  const int ty = t >> 4;
  float acc[4][4] = {};
#pragma unroll
  for (int k = 0; k < D; k++) {
    float a[4], bb[4];
#pragma unroll
    for (int r = 0; r < 4; r++) a[r] = xs[ty * 4 + r][k];
#pragma unroll
    for (int c = 0; c < 4; c++) bb[c] = ys[tx * 4 + c][k];
#pragma unroll
    for (int r = 0; r < 4; r++)
#pragma unroll
      for (int c = 0; c < 4; c++) {
        float d = a[r] - bb[c];
        acc[r][c] = fmaf(d, d, acc[r][c]);
      }
  }
#pragma unroll
  for (int r = 0; r < 4; r++) {
    float4 o = make_float4(acc[r][0], acc[r][1], acc[r][2], acc[r][3]);
    *(float4*)&C[((size_t)b * P + i0 + ty * 4 + r) * P + j0 + tx * 4] = o;
  }
}

// -------------------------------------------------------- fused u + v-partial
// 1024 blocks x 256 threads. Block owns 8 rows (bid*8..); thread t owns cols
// [8t, 8t+8). Writes u for its rows and one (m,s) col-partial per col.
// Partials: part[kb*8192 + gcol], kb = block index within batch (0..255).
__global__ __launch_bounds__(256, 4) void sweep8(
    const float* __restrict__ C, const float* __restrict__ v,
    float* __restrict__ u, float2* __restrict__ part, float elog) {
  const int bid = blockIdx.x;
  const int rows0 = bid * 8;          // global row base
  const int b = bid >> 8;             // batch (256 blocks per batch)
  const int kb = bid & 255;
  const int t = threadIdx.x;
  const int lane = t & 63;
  const int w = t >> 6;

  __shared__ float redm[4][8];
  __shared__ float reds[4][8];

  // v for my 8 cols, pre-scaled by KS (v=0 at iter 0 via memset)
  float vvK[8];
  {
    const float4* vp = (const float4*)(v + ((size_t)b << 11) + t * 8);
    float4 a = vp[0], q = vp[1];
    vvK[0] = a.x * KS; vvK[1] = a.y * KS; vvK[2] = a.z * KS; vvK[3] = a.w * KS;
    vvK[4] = q.x * KS; vvK[5] = q.y * KS; vvK[6] = q.z * KS; vvK[7] = q.w * KS;
  }

  // load 8 rows x 8 cols of C, pre-scaled by KS
  float cK[8][8];
  {
    const float* Cb = C + (size_t)rows0 * P + t * 8;
#pragma unroll
    for (int r = 0; r < 8; r++) {
      float4 a = *(const float4*)(Cb + (size_t)r * P);
      float4 q = *(const float4*)(Cb + (size_t)r * P + 4);
      cK[r][0] = a.x * KS; cK[r][1] = a.y * KS; cK[r][2] = a.z * KS; cK[r][3] = a.w * KS;
      cK[r][4] = q.x * KS; cK[r][5] = q.y * KS; cK[r][6] = q.z * KS; cK[r][7] = q.w * KS;
    }
  }

  // ---- phase A: exact row-LSE of z = vvK - cK (log2 domain)
  float bm[8];
#pragma unroll
  for (int r = 0; r < 8; r++) {
    float m = vvK[0] - cK[r][0];
#pragma unroll
    for (int j = 1; j < 8; j++) m = fmaxf(m, vvK[j] - cK[r][j]);
#pragma unroll
    for (int off = 32; off; off >>= 1) m = fmaxf(m, __shfl_xor(m, off));
    bm[r] = m;
  }
  if (lane == 0) {
#pragma unroll
    for (int r = 0; r < 8; r++) redm[w][r] = bm[r];
  }
  __syncthreads();
#pragma unroll
  for (int r = 0; r < 8; r++)
    bm[r] = fmaxf(fmaxf(redm[0][r], redm[1][r]),
                  fmaxf(redm[2][r], redm[3][r]));
  float ls[8];
#pragma unroll
  for (int r = 0; r < 8; r++) {
    float s = 0.f;
#pragma unroll
    for (int j = 0; j < 8; j++) s += EX2(vvK[j] - cK[r][j] - bm[r]);
#pragma unroll
    for (int off = 32; off; off >>= 1) s += __shfl_xor(s, off);
    ls[r] = s;
  }
  if (lane == 0) {
#pragma unroll
    for (int r = 0; r < 8; r++) reds[w][r] = ls[r];
  }
  __syncthreads();
  float urK[8];  // u * KS; raw u = urK * EL2 (since 1/KS == EL2)
#pragma unroll
  for (int r = 0; r < 8; r++) {
    float S = (reds[0][r] + reds[1][r]) + (reds[2][r] + reds[3][r]);
    urK[r] = (elog - EL2 * (bm[r] + LG2(S))) * KS;
  }
  if (t == 0) {
#pragma unroll
    for (int r = 0; r < 8; r++) u[rows0 + r] = urK[r] * EL2;
  }

  // ---- phase B: thread-local col-LSE partial over my 8 rows
  float2 pw[8];
#pragma unroll
  for (int cc = 0; cc < 8; cc++) {
    float z[8];
#pragma unroll
    for (int r = 0; r < 8; r++) z[r] = urK[r] - cK[r][cc];
    float tm = z[0];
#pragma unroll
    for (int r = 1; r < 8; r++) tm = fmaxf(tm, z[r]);
    float s = 0.f;
#pragma unroll
    for (int r = 0; r < 8; r++) s += EX2(z[r] - tm);
    pw[cc] = make_float2(tm, s);
  }
  {
    float4* p4 = (float4*)(part + (size_t)kb * (B * P) + ((size_t)b << 11) + t * 8);
#pragma unroll
    for (int i = 0; i < 4; i++)
      p4[i] = make_float4(pw[2 * i].x, pw[2 * i].y, pw[2 * i + 1].x, pw[2 * i + 1].y);
  }
}

// --------------------------------------------------------- v partial merge
// 128 blocks x 256. Block handles 64 consecutive global cols; wave w merges
// partial rows [w*64, w*64+64) for those cols (coalesced 512B per step),
// then LDS-combine the 4 wave results.
__global__ __launch_bounds__(256) void reduce_v2(
    const float2* __restrict__ part, float* __restrict__ v, float elog) {
  const int t = threadIdx.x;
  const int cl = t & 63;
  const int wv = t >> 6;
  const int col = blockIdx.x * 64 + cl;     // global col 0..8191
  const float2* pk = part + (size_t)wv * 64 * (B * P) + col;
  float m = -__builtin_inff();
  float s = 0.f;
#pragma unroll 8
  for (int i = 0; i < 64; i++) {
    float2 p = pk[(size_t)i * (B * P)];
    float M = fmaxf(m, p.x);
    s = s * EX2(m - M) + p.y * EX2(p.x - M);
    m = M;
  }
  __shared__ float mm[4][64];
  __shared__ float ss[4][64];
  mm[wv][cl] = m;
  ss[wv][cl] = s;
  __syncthreads();
  if (t < 64) {
    float M0 = mm[0][t], S0 = ss[0][t];
#pragma unroll
    for (int k = 1; k < 4; k++) {
      float pm = mm[k][t], ps = ss[k][t];
      float M = fmaxf(M0, pm);
      S0 = S0 * EX2(M0 - M) + ps * EX2(pm - M);
      M0 = M;
    }
    v[blockIdx.x * 64 + t] = elog - EL2 * (M0 + LG2(S0));
  }
}

// ------------------------------------------------------------------ epilogue
// 2048 blocks x 256. Block owns 4 rows; thread owns cols [8t,8t+8) (v cached).
__global__ __launch_bounds__(256) void final_pi2(
    const float* __restrict__ C, const float* __restrict__ u,
    const float* __restrict__ v, float* __restrict__ pi,
    float* __restrict__ cost) {
  const int bid = blockIdx.x;
  const int rows0 = bid * 4;
  const int b = rows0 >> 11;
  const int t = threadIdx.x;
  const int lane = t & 63;
  const int w = t >> 6;

  float vvK[8];
  {
    const float4* vp = (const float4*)(v + ((size_t)b << 11) + t * 8);
    float4 a = vp[0], q = vp[1];
    vvK[0] = a.x * KS; vvK[1] = a.y * KS; vvK[2] = a.z * KS; vvK[3] = a.w * KS;
    vvK[4] = q.x * KS; vvK[5] = q.y * KS; vvK[6] = q.z * KS; vvK[7] = q.w * KS;
  }

  float acc = 0.f;
#pragma unroll
  for (int r = 0; r < 4; r++) {
    const int row = rows0 + r;
    const float uK = u[row] * KS;
    const float* cp = C + (size_t)row * P + t * 8;
    float4 a = *(const float4*)(cp);
    float4 q = *(const float4*)(cp + 4);
    float c[8] = {a.x, a.y, a.z, a.w, q.x, q.y, q.z, q.w};
    float p[8];
#pragma unroll
    for (int j = 0; j < 8; j++) {
      p[j] = EX2(uK + vvK[j] - c[j] * KS);
      acc = fmaf(p[j], c[j], acc);
    }
    float* pp = pi + (size_t)row * P + t * 8;
    *(float4*)(pp) = make_float4(p[0], p[1], p[2], p[3]);
    *(float4*)(pp + 4) = make_float4(p[4], p[5], p[6], p[7]);
  }
#pragma unroll
  for (int off = 32; off; off >>= 1) acc += __shfl_xor(acc, off);
  __shared__ float sa[4];
  if (lane == 0) sa[w] = acc;
  __syncthreads();
  if (t == 0) atomicAdd(cost + b, (sa[0] + sa[1]) + (sa[2] + sa[3]));
}

// -------------------------------------------------------------------- launch
extern "C" void kernel_launch(void* const* d_in, const int* in_sizes, int n_in,
                              void* d_out, int out_size, void* d_ws,
                              size_t ws_size, hipStream_t stream) {
  const float* x = (const float*)d_in[0];
  const float* y = (const float*)d_in[1];
  float* out = (float*)d_out;
  float* cost = out;                          // [4]
  float* pi = out + 4;                        // [B*P*P], dead until epilogue
  float* Cmat = out + 4 + (size_t)B * P * P;  // [B*P*P]

  float2* part = (float2*)pi;                 // 256*8192 float2 = 16MB scratch
  float* v = (float*)d_ws;                    // [8192]
  float* u = v + B * P;                       // [8192]

  hipMemsetAsync(v, 0, B * P * sizeof(float), stream);
  hipMemsetAsync(cost, 0, 4 * sizeof(float), stream);

  dim3 cgrid(P / 64, P / 64, B);
  cost_kernel<<<cgrid, 256, 0, stream>>>(x, y, Cmat);

  const float elog = EPS * logf(1.0f / (float)P + 1e-8f);

  for (int it = 0; it < ITERS; it++) {
    sweep8<<<B * P / 8, 256, 0, stream>>>(Cmat, v, u, part, elog);
    reduce_v2<<<B * P / 64, 256, 0, stream>>>(part, v, elog);
  }

  final_pi2<<<B * P / 4, 256, 0, stream>>>(Cmat, u, v, pi, cost);
}

// Round 6
// 2713.264 us; speedup vs baseline: 5.1329x; 1.4926x over previous
//
#include <hip/hip_runtime.h>
#include <hip/hip_bf16.h>
#include <math.h>

// Sinkhorn distance, B=4, P1=P2=2048, D=64, EPS=0.1, 100 iterations.
// d_out layout: cost[4] | pi[4*2048*2048] | C[4*2048*2048]
//
// v5: v4 structure with the spill fixed and scaled-domain u/v.
//  - sweep8: 8 rows/block, 1024 blocks, __launch_bounds__(256,3) (v4's (256,4)
//    capped VGPR at 128 < ~140 live set -> scratch spill -> 4049us regression).
//  - u,v stored pre-scaled: uK = u/(eps*ln2), vK likewise. Update becomes
//    uK = elogK - m - log2(S), elogK = log2(1/P + 1e-8). No KS/EL2 muls on
//    the u/v path anywhere.
//  - reduce_v3: 512 blocks, 16 threads/col, 16-deep serial merge chains
//    (v4: 128 blocks, 64-deep), shfl + LDS combine.
// Math identical to the passing v2/v4: log2-domain exact-max LSE; the u/eps
// term cancels, so uK_new depends only on vK (and vice versa).

#define P 2048
#define D 64
#define B 4
#define ITERS 100
#define EPS 0.1f
// (1/eps) * log2(e) = 1/(eps*ln2): multiplies C into the log2 domain
#define KS 14.426950408889634f
// eps * ln(2) == 1/KS
#define EL2 0.06931471805599453f

#define EX2 __builtin_amdgcn_exp2f   // v_exp_f32 (2^x)
#define LG2 __builtin_amdgcn_logf    // v_log_f32 (log2 x)

// ---------------------------------------------------------------- cost matrix
// grid (32, 32, 4), block 256. 64x64 tile, 4x4 per thread.
__global__ __launch_bounds__(256) void cost_kernel(
    const float* __restrict__ X, const float* __restrict__ Y,
    float* __restrict__ C) {
  __shared__ float xs[64][65];
  __shared__ float ys[64][65];
  const int b = blockIdx.z;
  const int i0 = blockIdx.y * 64;
  const int j0 = blockIdx.x * 64;
  const float* Xb = X + ((size_t)b * P + i0) * D;
  const float* Yb = Y + ((size_t)b * P + j0) * D;
  const int t = threadIdx.x;
#pragma unroll
  for (int n = 0; n < 4; n++) {
    int e4 = t + n * 256;
    float4 xv = ((const float4*)Xb)[e4];
    float4 yv = ((const float4*)Yb)[e4];
    int r = e4 >> 4;
    int k = (e4 & 15) * 4;
    xs[r][k] = xv.x; xs[r][k + 1] = xv.y; xs[r][k + 2] = xv.z; xs[r][k + 3] = xv.w;
    ys[r][k] = yv.x; ys[r][k + 1] = yv.y; ys[r][k + 2] = yv.z; ys[r][k + 3] = yv.w;
  }
  __syncthreads();
  const int tx = t & 15;
  const int ty = t >> 4;
  float acc[4][4] = {};
#pragma unroll
  for (int k = 0; k < D; k++) {
    float a[4], bb[4];
#pragma unroll
    for (int r = 0; r < 4; r++) a[r] = xs[ty * 4 + r][k];
#pragma unroll
    for (int c = 0; c < 4; c++) bb[c] = ys[tx * 4 + c][k];
#pragma unroll
    for (int r = 0; r < 4; r++)
#pragma unroll
      for (int c = 0; c < 4; c++) {
        float d = a[r] - bb[c];
        acc[r][c] = fmaf(d, d, acc[r][c]);
      }
  }
#pragma unroll
  for (int r = 0; r < 4; r++) {
    float4 o = make_float4(acc[r][0], acc[r][1], acc[r][2], acc[r][3]);
    *(float4*)&C[((size_t)b * P + i0 + ty * 4 + r) * P + j0 + tx * 4] = o;
  }
}

// -------------------------------------------------------- fused u + v-partial
// 1024 blocks x 256 threads, 3 blocks/CU min. Block owns 8 rows; thread t
// owns cols [8t, 8t+8). Writes uK for its rows and one (m,s) partial per col.
__global__ __launch_bounds__(256, 3) void sweep8(
    const float* __restrict__ C, const float* __restrict__ vK,
    float* __restrict__ uK, float2* __restrict__ part, float elogK) {
  const int bid = blockIdx.x;
  const int rows0 = bid * 8;          // global row base
  const int b = bid >> 8;             // batch (256 blocks per batch)
  const int kb = bid & 255;
  const int t = threadIdx.x;
  const int lane = t & 63;
  const int w = t >> 6;

  __shared__ float redm[4][8];
  __shared__ float reds[4][8];

  // vK for my 8 cols (already scaled; zero at iter 0 via memset)
  float vv[8];
  {
    const float4* vp = (const float4*)(vK + ((size_t)b << 11) + t * 8);
    float4 a = vp[0], q = vp[1];
    vv[0] = a.x; vv[1] = a.y; vv[2] = a.z; vv[3] = a.w;
    vv[4] = q.x; vv[5] = q.y; vv[6] = q.z; vv[7] = q.w;
  }

  // load 8 rows x 8 cols of C, scaled into log2 domain
  float cK[8][8];
  {
    const float* Cb = C + (size_t)rows0 * P + t * 8;
#pragma unroll
    for (int r = 0; r < 8; r++) {
      float4 a = *(const float4*)(Cb + (size_t)r * P);
      float4 q = *(const float4*)(Cb + (size_t)r * P + 4);
      cK[r][0] = a.x * KS; cK[r][1] = a.y * KS; cK[r][2] = a.z * KS; cK[r][3] = a.w * KS;
      cK[r][4] = q.x * KS; cK[r][5] = q.y * KS; cK[r][6] = q.z * KS; cK[r][7] = q.w * KS;
    }
  }

  // ---- phase A: exact row-LSE of z = vv - cK (log2 domain) -> uK rows
  float bm[8];
#pragma unroll
  for (int r = 0; r < 8; r++) {
    float m = vv[0] - cK[r][0];
#pragma unroll
    for (int j = 1; j < 8; j++) m = fmaxf(m, vv[j] - cK[r][j]);
#pragma unroll
    for (int off = 32; off; off >>= 1) m = fmaxf(m, __shfl_xor(m, off));
    bm[r] = m;
  }
  if (lane == 0) {
#pragma unroll
    for (int r = 0; r < 8; r++) redm[w][r] = bm[r];
  }
  __syncthreads();
#pragma unroll
  for (int r = 0; r < 8; r++)
    bm[r] = fmaxf(fmaxf(redm[0][r], redm[1][r]),
                  fmaxf(redm[2][r], redm[3][r]));
  float ls[8];
#pragma unroll
  for (int r = 0; r < 8; r++) {
    float s = 0.f;
#pragma unroll
    for (int j = 0; j < 8; j++) s += EX2(vv[j] - cK[r][j] - bm[r]);
#pragma unroll
    for (int off = 32; off; off >>= 1) s += __shfl_xor(s, off);
    ls[r] = s;
  }
  if (lane == 0) {
#pragma unroll
    for (int r = 0; r < 8; r++) reds[w][r] = ls[r];
  }
  __syncthreads();
  float ur[8];  // uK for my 8 rows
#pragma unroll
  for (int r = 0; r < 8; r++) {
    float S = (reds[0][r] + reds[1][r]) + (reds[2][r] + reds[3][r]);
    ur[r] = elogK - bm[r] - LG2(S);
  }
  if (t == 0) {
#pragma unroll
    for (int r = 0; r < 8; r++) uK[rows0 + r] = ur[r];
  }

  // ---- phase B: thread-local col-LSE partial over my 8 rows, write pairs
  float4* p4 = (float4*)(part + (size_t)kb * (B * P) + ((size_t)b << 11) + t * 8);
#pragma unroll
  for (int i = 0; i < 4; i++) {
    float m0, s0, m1, s1;
    {
      const int cc = 2 * i;
      float z[8];
#pragma unroll
      for (int r = 0; r < 8; r++) z[r] = ur[r] - cK[r][cc];
      m0 = z[0];
#pragma unroll
      for (int r = 1; r < 8; r++) m0 = fmaxf(m0, z[r]);
      s0 = 0.f;
#pragma unroll
      for (int r = 0; r < 8; r++) s0 += EX2(z[r] - m0);
    }
    {
      const int cc = 2 * i + 1;
      float z[8];
#pragma unroll
      for (int r = 0; r < 8; r++) z[r] = ur[r] - cK[r][cc];
      m1 = z[0];
#pragma unroll
      for (int r = 1; r < 8; r++) m1 = fmaxf(m1, z[r]);
      s1 = 0.f;
#pragma unroll
      for (int r = 0; r < 8; r++) s1 += EX2(z[r] - m1);
    }
    p4[i] = make_float4(m0, s0, m1, s1);
  }
}

// --------------------------------------------------------- v partial merge
// 512 blocks x 256. Block owns 16 consecutive global cols; 16 threads/col.
// c = t&15 (coalesced), seg = t>>4 merges partials [seg*16, seg*16+16).
// Combine: shfl_xor(16,32) merges 4 segs/wave, LDS combines the 4 waves.
__global__ __launch_bounds__(256) void reduce_v3(
    const float2* __restrict__ part, float* __restrict__ vK, float elogK) {
  const int t = threadIdx.x;
  const int c = t & 15;
  const int seg = t >> 4;            // 0..15
  const int col = blockIdx.x * 16 + c;
  const float2* pk = part + (size_t)(seg * 16) * (B * P) + col;
  float m = -__builtin_inff();
  float s = 0.f;
#pragma unroll
  for (int i = 0; i < 16; i++) {
    float2 p = pk[(size_t)i * (B * P)];
    float M = fmaxf(m, p.x);
    s = s * EX2(m - M) + p.y * EX2(p.x - M);
    m = M;
  }
  // merge 4 segs within each wave (lane^16 -> seg^1, lane^32 -> seg^2)
#pragma unroll
  for (int off = 16; off <= 32; off <<= 1) {
    float om = __shfl_xor(m, off);
    float os = __shfl_xor(s, off);
    float M = fmaxf(m, om);
    s = s * EX2(m - M) + os * EX2(om - M);
    m = M;
  }
  __shared__ float mm[4][16];
  __shared__ float ss[4][16];
  if ((t & 63) < 16) {               // lane c of each wave
    mm[t >> 6][c] = m;
    ss[t >> 6][c] = s;
  }
  __syncthreads();
  if (t < 16) {
    float M0 = mm[0][t], S0 = ss[0][t];
#pragma unroll
    for (int k = 1; k < 4; k++) {
      float pm = mm[k][t], ps = ss[k][t];
      float M = fmaxf(M0, pm);
      S0 = S0 * EX2(M0 - M) + ps * EX2(pm - M);
      M0 = M;
    }
    vK[blockIdx.x * 16 + t] = elogK - M0 - LG2(S0);
  }
}

// ------------------------------------------------------------------ epilogue
// 2048 blocks x 256. Block owns 4 rows; thread owns cols [8t,8t+8).
__global__ __launch_bounds__(256) void final_pi2(
    const float* __restrict__ C, const float* __restrict__ uK,
    const float* __restrict__ vK, float* __restrict__ pi,
    float* __restrict__ cost) {
  const int bid = blockIdx.x;
  const int rows0 = bid * 4;
  const int b = rows0 >> 11;
  const int t = threadIdx.x;
  const int lane = t & 63;
  const int w = t >> 6;

  float vv[8];
  {
    const float4* vp = (const float4*)(vK + ((size_t)b << 11) + t * 8);
    float4 a = vp[0], q = vp[1];
    vv[0] = a.x; vv[1] = a.y; vv[2] = a.z; vv[3] = a.w;
    vv[4] = q.x; vv[5] = q.y; vv[6] = q.z; vv[7] = q.w;
  }

  float acc = 0.f;
#pragma unroll
  for (int r = 0; r < 4; r++) {
    const int row = rows0 + r;
    const float u = uK[row];
    const float* cp = C + (size_t)row * P + t * 8;
    float4 a = *(const float4*)(cp);
    float4 q = *(const float4*)(cp + 4);
    float c[8] = {a.x, a.y, a.z, a.w, q.x, q.y, q.z, q.w};
    float p[8];
#pragma unroll
    for (int j = 0; j < 8; j++) {
      p[j] = EX2(u + vv[j] - c[j] * KS);
      acc = fmaf(p[j], c[j], acc);
    }
    float* pp = pi + (size_t)row * P + t * 8;
    *(float4*)(pp) = make_float4(p[0], p[1], p[2], p[3]);
    *(float4*)(pp + 4) = make_float4(p[4], p[5], p[6], p[7]);
  }
#pragma unroll
  for (int off = 32; off; off >>= 1) acc += __shfl_xor(acc, off);
  __shared__ float sa[4];
  if (lane == 0) sa[w] = acc;
  __syncthreads();
  if (t == 0) atomicAdd(cost + b, (sa[0] + sa[1]) + (sa[2] + sa[3]));
}

// -------------------------------------------------------------------- launch
extern "C" void kernel_launch(void* const* d_in, const int* in_sizes, int n_in,
                              void* d_out, int out_size, void* d_ws,
                              size_t ws_size, hipStream_t stream) {
  const float* x = (const float*)d_in[0];
  const float* y = (const float*)d_in[1];
  float* out = (float*)d_out;
  float* cost = out;                          // [4]
  float* pi = out + 4;                        // [B*P*P], dead until epilogue
  float* Cmat = out + 4 + (size_t)B * P * P;  // [B*P*P]

  float2* part = (float2*)pi;                 // 256*8192 float2 = 16MB scratch
  float* vK = (float*)d_ws;                   // [8192] scaled v
  float* uK = vK + B * P;                     // [8192] scaled u

  hipMemsetAsync(vK, 0, B * P * sizeof(float), stream);
  hipMemsetAsync(cost, 0, 4 * sizeof(float), stream);

  dim3 cgrid(P / 64, P / 64, B);
  cost_kernel<<<cgrid, 256, 0, stream>>>(x, y, Cmat);

  // elogK = log_mu / (eps*ln2) = log2(1/P + 1e-8)
  const float elogK = log2f(1.0f / (float)P + 1e-8f);

  for (int it = 0; it < ITERS; it++) {
    sweep8<<<B * P / 8, 256, 0, stream>>>(Cmat, vK, uK, part, elogK);
    reduce_v3<<<B * P / 16, 256, 0, stream>>>(part, vK, elogK);
  }

  final_pi2<<<B * P / 4, 256, 0, stream>>>(Cmat, uK, vK, pi, cost);
}